// Round 1
// baseline (2556.205 us; speedup 1.0000x reference)
//
#include <hip/hip_runtime.h>
#include <math.h>

// Problem constants (fixed by the reference)
constexpr int Bb  = 2;
constexpr int Ss  = 2048;
constexpr int Dd  = 2048;
constexpr int Hh  = 16;
constexpr int DHd = 128;
constexpr int BS  = Bb * Ss;   // 4096

// ---------------------------------------------------------------------------
// GEMM: C[M][N] = A[M][K] @ Bw[N][K]^T + bias[N]   (all fp32, row-major)
// Tile 64x64x16, 256 threads, 4x4 outputs/thread, float4 LDS reads.
// ---------------------------------------------------------------------------
#define GBM 64
#define GBN 64
#define GBK 16

__global__ __launch_bounds__(256) void gemm_bt_f32(
    const float* __restrict__ A, const float* __restrict__ Bw,
    const float* __restrict__ bias, float* __restrict__ C,
    int M, int N, int K)
{
  // pad to 20 floats/row: keeps float4 alignment (80B rows) and breaks bank alias
  __shared__ float As[GBM][GBK + 4];
  __shared__ float Bs[GBN][GBK + 4];

  const int tid = threadIdx.x;
  const int ty  = tid >> 4;    // 0..15
  const int tx  = tid & 15;    // 0..15
  const int m0  = blockIdx.y * GBM;
  const int n0  = blockIdx.x * GBN;
  const int lrow = tid >> 2;       // 0..63
  const int lk   = (tid & 3) << 2; // 0,4,8,12

  float acc[4][4];
#pragma unroll
  for (int i = 0; i < 4; i++)
#pragma unroll
    for (int j = 0; j < 4; j++) acc[i][j] = 0.0f;

  const float* aptr = A  + (size_t)(m0 + lrow) * K + lk;
  const float* bptr = Bw + (size_t)(n0 + lrow) * K + lk;

  for (int k0 = 0; k0 < K; k0 += GBK) {
    float4 av = *(const float4*)(aptr + k0);
    float4 bv = *(const float4*)(bptr + k0);
    __syncthreads();  // previous iteration's readers done
    *(float4*)&As[lrow][lk] = av;
    *(float4*)&Bs[lrow][lk] = bv;
    __syncthreads();
#pragma unroll
    for (int kk = 0; kk < GBK; kk += 4) {
      float4 a[4], b[4];
#pragma unroll
      for (int i = 0; i < 4; i++) a[i] = *(const float4*)&As[ty + 16 * i][kk];
#pragma unroll
      for (int j = 0; j < 4; j++) b[j] = *(const float4*)&Bs[tx + 16 * j][kk];
#pragma unroll
      for (int i = 0; i < 4; i++)
#pragma unroll
        for (int j = 0; j < 4; j++) {
          acc[i][j] += a[i].x * b[j].x + a[i].y * b[j].y +
                       a[i].z * b[j].z + a[i].w * b[j].w;
        }
    }
  }

#pragma unroll
  for (int i = 0; i < 4; i++) {
    const int row = m0 + ty + 16 * i;
#pragma unroll
    for (int j = 0; j < 4; j++) {
      const int col = n0 + tx + 16 * j;
      C[(size_t)row * N + col] = acc[i][j] + bias[col];
    }
  }
}

// ---------------------------------------------------------------------------
// RoPE: in-place on q (B,S,H,DH) and on k half of kv (B,S,256: k=[0,128), v=[128,256))
// One block per (b,s) row, 64 threads; thread i owns the (i, i+64) pair.
// ---------------------------------------------------------------------------
__global__ __launch_bounds__(64) void rope_kernel(
    float* __restrict__ q, float* __restrict__ kv, int S)
{
  const int row = blockIdx.x;        // b*S + s
  const int s   = row & (S - 1);     // S = 2048 (pow2)
  const int i   = threadIdx.x;       // 0..63

  const float invf = powf(10000.0f, -(float)i * (1.0f / 64.0f));
  const float ang  = (float)s * invf;
  const float c  = cosf(ang);
  const float sn = sinf(ang);

#pragma unroll
  for (int h = 0; h < Hh; h++) {
    const size_t base = ((size_t)row * Hh + h) * DHd;
    const float lo = q[base + i];
    const float hi = q[base + i + 64];
    q[base + i]      = lo * c - hi * sn;   // rotate_half: lo' = lo*c + (-hi)*s
    q[base + i + 64] = hi * c + lo * sn;   // hi' = hi*c + lo*s
  }
  const size_t kb = (size_t)row * 256;
  const float lo = kv[kb + i];
  const float hi = kv[kb + i + 64];
  kv[kb + i]      = lo * c - hi * sn;
  kv[kb + i + 64] = hi * c + lo * sn;
}

// ---------------------------------------------------------------------------
// Flash-style causal MQA attention (fp32).
// Grid: (S/64, H, B). Block: 256 threads. Q tile 64 rows; K/V tiles 32.
// Per thread: score block rows ty+16i (i<4), cols tx+16jj (jj<2);
// O block rows ty+16i, cols tx*4+j and 64+tx*4+j.
// ---------------------------------------------------------------------------
#define QT 64
#define KT 32

__global__ __launch_bounds__(256) void flash_attn_f32(
    const float* __restrict__ q,    // (B,S,H,DH) roped
    const float* __restrict__ kv,   // (B,S,256): k roped in [0,128), v in [128,256)
    float* __restrict__ attn)       // (B,S,H,DH)
{
  __shared__ float Qs[QT][DHd + 4];   // stride 132
  __shared__ float Ks[KT][DHd + 4];
  __shared__ float Vs[KT][DHd + 4];
  __shared__ float Ps[QT][KT + 4];    // stride 36

  const int qt = blockIdx.x, h = blockIdx.y, b = blockIdx.z;
  const int q0 = qt * QT;
  const int tid = threadIdx.x;
  const int ty = tid >> 4, tx = tid & 15;

  // stage Q tile: 64 rows x 128 cols
  for (int cch = tid; cch < QT * 32; cch += 256) {
    const int r = cch >> 5, col = (cch & 31) << 2;
    *(float4*)&Qs[r][col] =
        *(const float4*)&q[(((size_t)b * Ss + q0 + r) * Hh + h) * DHd + col];
  }

  float m_i[4], l_i[4], O[4][8];
#pragma unroll
  for (int i = 0; i < 4; i++) {
    m_i[i] = -1e30f; l_i[i] = 0.0f;
#pragma unroll
    for (int j = 0; j < 8; j++) O[i][j] = 0.0f;
  }
  const float scale = 0.08838834764831845f;  // 1/sqrt(128)

  const int jmax = q0 + QT;
  for (int j0 = 0; j0 < jmax; j0 += KT) {
    __syncthreads();  // previous tile's consumers done (also covers Qs store)
    // stage K,V tile: 32 rows x 128 cols each
    for (int cch = tid; cch < KT * 32; cch += 256) {
      const int r = cch >> 5, col = (cch & 31) << 2;
      const float* src = &kv[((size_t)b * Ss + j0 + r) * 256];
      *(float4*)&Ks[r][col] = *(const float4*)&src[col];
      *(float4*)&Vs[r][col] = *(const float4*)&src[128 + col];
    }
    __syncthreads();

    // scores
    float sc[4][2];
#pragma unroll
    for (int i = 0; i < 4; i++) { sc[i][0] = 0.0f; sc[i][1] = 0.0f; }
    for (int kk = 0; kk < DHd; kk += 4) {
      float4 a[4], bb[2];
#pragma unroll
      for (int i = 0; i < 4; i++) a[i] = *(const float4*)&Qs[ty + 16 * i][kk];
#pragma unroll
      for (int jj = 0; jj < 2; jj++) bb[jj] = *(const float4*)&Ks[tx + 16 * jj][kk];
#pragma unroll
      for (int i = 0; i < 4; i++)
#pragma unroll
        for (int jj = 0; jj < 2; jj++) {
          sc[i][jj] += a[i].x * bb[jj].x + a[i].y * bb[jj].y +
                       a[i].z * bb[jj].z + a[i].w * bb[jj].w;
        }
    }

    // scale + causal mask
#pragma unroll
    for (int i = 0; i < 4; i++) {
      const int gr = q0 + ty + 16 * i;
#pragma unroll
      for (int jj = 0; jj < 2; jj++) {
        const int gc = j0 + tx + 16 * jj;
        sc[i][jj] = (gc <= gr) ? sc[i][jj] * scale : -1e30f;
      }
    }

    // online softmax: row reduce over 16 tx lanes
    float mt[4];
#pragma unroll
    for (int i = 0; i < 4; i++) mt[i] = fmaxf(sc[i][0], sc[i][1]);
#pragma unroll
    for (int off = 1; off < 16; off <<= 1)
#pragma unroll
      for (int i = 0; i < 4; i++) mt[i] = fmaxf(mt[i], __shfl_xor(mt[i], off));

    float alpha[4], p[4][2], rs[4];
#pragma unroll
    for (int i = 0; i < 4; i++) {
      const float mnew = fmaxf(m_i[i], mt[i]);
      alpha[i] = expf(m_i[i] - mnew);
      m_i[i] = mnew;
      p[i][0] = expf(sc[i][0] - mnew);
      p[i][1] = expf(sc[i][1] - mnew);
      rs[i] = p[i][0] + p[i][1];
    }
#pragma unroll
    for (int off = 1; off < 16; off <<= 1)
#pragma unroll
      for (int i = 0; i < 4; i++) rs[i] += __shfl_xor(rs[i], off);
#pragma unroll
    for (int i = 0; i < 4; i++) {
      l_i[i] = l_i[i] * alpha[i] + rs[i];
#pragma unroll
      for (int j = 0; j < 8; j++) O[i][j] *= alpha[i];
      Ps[ty + 16 * i][tx]      = p[i][0];
      Ps[ty + 16 * i][tx + 16] = p[i][1];
    }
    __syncthreads();

    // O += P @ V
    for (int kk = 0; kk < KT; kk++) {
      float pr[4];
#pragma unroll
      for (int i = 0; i < 4; i++) pr[i] = Ps[ty + 16 * i][kk];
      const float4 v0 = *(const float4*)&Vs[kk][tx * 4];
      const float4 v1 = *(const float4*)&Vs[kk][64 + tx * 4];
#pragma unroll
      for (int i = 0; i < 4; i++) {
        O[i][0] += pr[i] * v0.x; O[i][1] += pr[i] * v0.y;
        O[i][2] += pr[i] * v0.z; O[i][3] += pr[i] * v0.w;
        O[i][4] += pr[i] * v1.x; O[i][5] += pr[i] * v1.y;
        O[i][6] += pr[i] * v1.z; O[i][7] += pr[i] * v1.w;
      }
    }
  }

  // epilogue: normalize and store
#pragma unroll
  for (int i = 0; i < 4; i++) {
    const float inv = 1.0f / l_i[i];
    const int row = q0 + ty + 16 * i;
    float* dst = &attn[(((size_t)b * Ss + row) * Hh + h) * DHd];
    float4 o0, o1;
    o0.x = O[i][0] * inv; o0.y = O[i][1] * inv; o0.z = O[i][2] * inv; o0.w = O[i][3] * inv;
    o1.x = O[i][4] * inv; o1.y = O[i][5] * inv; o1.z = O[i][6] * inv; o1.w = O[i][7] * inv;
    *(float4*)&dst[tx * 4]      = o0;
    *(float4*)&dst[64 + tx * 4] = o1;
  }
}

// ---------------------------------------------------------------------------
extern "C" void kernel_launch(void* const* d_in, const int* in_sizes, int n_in,
                              void* d_out, int out_size, void* d_ws, size_t ws_size,
                              hipStream_t stream) {
  const float* x   = (const float*)d_in[0];   // (B,S,D)
  const float* qw  = (const float*)d_in[1];   // (H*DH, D)
  const float* qb  = (const float*)d_in[2];   // (H*DH,)
  const float* kvw = (const float*)d_in[3];   // (256, D)
  const float* kvb = (const float*)d_in[4];   // (256,)
  const float* ow  = (const float*)d_in[5];   // (D, H*DH)
  const float* ob  = (const float*)d_in[6];   // (D,)
  float* out = (float*)d_out;

  // workspace layout (fp32): q_buf (BS x 2048), kv_buf (BS x 256), attn_buf (BS x 2048)
  float* q_buf    = (float*)d_ws;
  float* kv_buf   = q_buf + (size_t)BS * Dd;
  float* attn_buf = kv_buf + (size_t)BS * 256;
  // total: (8388608 + 1048576 + 8388608) * 4 B = 71.3 MB

  // Q projection: (4096 x 2048) = x @ qw^T + qb
  gemm_bt_f32<<<dim3(Dd / GBN, BS / GBM), 256, 0, stream>>>(
      x, qw, qb, q_buf, BS, Dd, Dd);
  // KV projection: (4096 x 256)
  gemm_bt_f32<<<dim3(256 / GBN, BS / GBM), 256, 0, stream>>>(
      x, kvw, kvb, kv_buf, BS, 256, Dd);
  // RoPE in-place on q and k
  rope_kernel<<<BS, 64, 0, stream>>>(q_buf, kv_buf, Ss);
  // causal MQA flash attention
  flash_attn_f32<<<dim3(Ss / QT, Hh, Bb), 256, 0, stream>>>(q_buf, kv_buf, attn_buf);
  // O projection: out = attn @ ow^T + ob
  gemm_bt_f32<<<dim3(Dd / GBN, BS / GBM), 256, 0, stream>>>(
      attn_buf, ow, ob, out, BS, Dd, Dd);
}

// Round 2
// 1417.144 us; speedup vs baseline: 1.8038x; 1.8038x over previous
//
#include <hip/hip_runtime.h>
#include <math.h>

// Problem constants (fixed by the reference)
constexpr int Bb  = 2;
constexpr int Ss  = 2048;
constexpr int Dd  = 2048;
constexpr int Hh  = 16;
constexpr int DHd = 128;
constexpr int BS  = Bb * Ss;   // 4096

typedef __bf16 bf16x8 __attribute__((ext_vector_type(8)));
typedef float  f32x4  __attribute__((ext_vector_type(4)));

// fp32 -> bf16 (RNE), bit-level (no header dependency)
static __device__ __forceinline__ unsigned short f2bf(float f) {
  union { float f; unsigned int u; } a; a.f = f;
  unsigned int u = a.u;
  unsigned int r = (u + 0x7fffu + ((u >> 16) & 1u)) >> 16;
  return (unsigned short)r;
}

// ---------------------------------------------------------------------------
// cast fp32 -> bf16, one float4 per thread
// ---------------------------------------------------------------------------
__global__ __launch_bounds__(256) void cast_f32_bf16(
    const float* __restrict__ src, unsigned short* __restrict__ dst, int n4)
{
  const int i = blockIdx.x * 256 + threadIdx.x;
  if (i >= n4) return;
  const float4 v = ((const float4*)src)[i];
  ushort4 o;
  o.x = f2bf(v.x); o.y = f2bf(v.y); o.z = f2bf(v.z); o.w = f2bf(v.w);
  ((ushort4*)dst)[i] = o;
}

// ---------------------------------------------------------------------------
// bf16 MFMA GEMM: C[M][N] = A[M][K] @ Bw[N][K]^T + bias[N], fp32 out.
// 128x128 tile, BK=32, 256 threads (4 waves, 2x2 quadrants of 64x64),
// global_load_lds width-16 staging (m97 structure).
// ---------------------------------------------------------------------------
#define TM 128
#define TN 128
#define TK 32

#define GLOAD16(gp, lp)                                                        \
  __builtin_amdgcn_global_load_lds(                                            \
      (const __attribute__((address_space(1))) void*)(gp),                     \
      (__attribute__((address_space(3))) void*)(lp), 16, 0, 0)

__global__ __launch_bounds__(256) void gemm_bt_mfma(
    const unsigned short* __restrict__ A,    // M x K bf16
    const unsigned short* __restrict__ Bw,   // N x K bf16
    const float* __restrict__ bias,          // N
    float* __restrict__ C,                   // M x N fp32
    int M, int N, int K)
{
  __shared__ unsigned short As[TM * TK];   // 8 KB
  __shared__ unsigned short Bs[TN * TK];   // 8 KB

  const int tid  = threadIdx.x;
  const int w    = tid >> 6;      // wave 0..3
  const int lane = tid & 63;
  const int m0   = blockIdx.y * TM;
  const int n0   = blockIdx.x * TN;
  const int wm   = (w >> 1) * 64; // wave quadrant within tile
  const int wn   = (w & 1) * 64;

  f32x4 acc[4][4];
#pragma unroll
  for (int i = 0; i < 4; i++)
#pragma unroll
    for (int j = 0; j < 4; j++) acc[i][j] = (f32x4){0.f, 0.f, 0.f, 0.f};

  // staging: each wave stages 16 rows per call, 2 calls each for A and B.
  // lane L covers row (L>>2), 16B chunk (L&3) -> LDS byte base + 16*L (contiguous)
  const int srow = lane >> 2;          // 0..15
  const int scol = (lane & 3) * 8;     // bf16 element offset within row
  const unsigned short* aG0 = A  + (size_t)(m0 +      w * 16 + srow) * K + scol;
  const unsigned short* aG1 = A  + (size_t)(m0 + 64 + w * 16 + srow) * K + scol;
  const unsigned short* bG0 = Bw + (size_t)(n0 +      w * 16 + srow) * K + scol;
  const unsigned short* bG1 = Bw + (size_t)(n0 + 64 + w * 16 + srow) * K + scol;
  unsigned short* aL0 = &As[(     w * 16) * TK];   // wave-uniform LDS bases
  unsigned short* aL1 = &As[(64 + w * 16) * TK];
  unsigned short* bL0 = &Bs[(     w * 16) * TK];
  unsigned short* bL1 = &Bs[(64 + w * 16) * TK];

  // fragment addressing (16x16x32): row/col = lane&15, k = (lane>>4)*8 + j
  const int fr = lane & 15;
  const int fk = (lane >> 4) * 8;

  for (int k0 = 0; k0 < K; k0 += TK) {
    __syncthreads();                 // previous iteration's LDS readers done
    GLOAD16(aG0 + k0, aL0);
    GLOAD16(aG1 + k0, aL1);
    GLOAD16(bG0 + k0, bL0);
    GLOAD16(bG1 + k0, bL1);
    __syncthreads();                 // compiler drains vmcnt(0) before barrier

    bf16x8 af[4], bfr[4];
#pragma unroll
    for (int i = 0; i < 4; i++)
      af[i] = *(const bf16x8*)&As[(wm + i * 16 + fr) * TK + fk];
#pragma unroll
    for (int j = 0; j < 4; j++)
      bfr[j] = *(const bf16x8*)&Bs[(wn + j * 16 + fr) * TK + fk];
#pragma unroll
    for (int i = 0; i < 4; i++)
#pragma unroll
      for (int j = 0; j < 4; j++)
        acc[i][j] = __builtin_amdgcn_mfma_f32_16x16x32_bf16(
            af[i], bfr[j], acc[i][j], 0, 0, 0);
  }

  // epilogue: C/D layout col=lane&15, row=(lane>>4)*4+reg
  const int er = (lane >> 4) * 4;
  const int ec = lane & 15;
#pragma unroll
  for (int j = 0; j < 4; j++) {
    const int col = n0 + wn + j * 16 + ec;
    const float bv = bias[col];
#pragma unroll
    for (int i = 0; i < 4; i++) {
      const int rbase = m0 + wm + i * 16 + er;
#pragma unroll
      for (int r = 0; r < 4; r++)
        C[(size_t)(rbase + r) * N + col] = acc[i][j][r] + bv;
    }
  }
}

// ---------------------------------------------------------------------------
// RoPE: in-place on q (B,S,H,DH) and on k half of kv (B,S,256)
// ---------------------------------------------------------------------------
__global__ __launch_bounds__(64) void rope_kernel(
    float* __restrict__ q, float* __restrict__ kv, int S)
{
  const int row = blockIdx.x;        // b*S + s
  const int s   = row & (S - 1);
  const int i   = threadIdx.x;       // 0..63

  const float invf = powf(10000.0f, -(float)i * (1.0f / 64.0f));
  const float ang  = (float)s * invf;
  const float c  = cosf(ang);
  const float sn = sinf(ang);

#pragma unroll
  for (int h = 0; h < Hh; h++) {
    const size_t base = ((size_t)row * Hh + h) * DHd;
    const float lo = q[base + i];
    const float hi = q[base + i + 64];
    q[base + i]      = lo * c - hi * sn;
    q[base + i + 64] = hi * c + lo * sn;
  }
  const size_t kb = (size_t)row * 256;
  const float lo = kv[kb + i];
  const float hi = kv[kb + i + 64];
  kv[kb + i]      = lo * c - hi * sn;
  kv[kb + i + 64] = hi * c + lo * sn;
}

// ---------------------------------------------------------------------------
// Flash-style causal MQA attention (fp32 math), bf16 output for O-projection.
// Grid: (S/64, H, B). Block: 256 threads. Q tile 64 rows; K/V tiles 32.
// ---------------------------------------------------------------------------
#define QT 64
#define KT 32

__global__ __launch_bounds__(256) void flash_attn_f32(
    const float* __restrict__ q,          // (B,S,H,DH) roped
    const float* __restrict__ kv,         // (B,S,256): k [0,128), v [128,256)
    unsigned short* __restrict__ attn)    // (B,S,H,DH) bf16
{
  __shared__ float Qs[QT][DHd + 4];
  __shared__ float Ks[KT][DHd + 4];
  __shared__ float Vs[KT][DHd + 4];
  __shared__ float Ps[QT][KT + 4];

  const int qt = blockIdx.x, h = blockIdx.y, b = blockIdx.z;
  const int q0 = qt * QT;
  const int tid = threadIdx.x;
  const int ty = tid >> 4, tx = tid & 15;

  for (int cch = tid; cch < QT * 32; cch += 256) {
    const int r = cch >> 5, col = (cch & 31) << 2;
    *(float4*)&Qs[r][col] =
        *(const float4*)&q[(((size_t)b * Ss + q0 + r) * Hh + h) * DHd + col];
  }

  float m_i[4], l_i[4], O[4][8];
#pragma unroll
  for (int i = 0; i < 4; i++) {
    m_i[i] = -1e30f; l_i[i] = 0.0f;
#pragma unroll
    for (int j = 0; j < 8; j++) O[i][j] = 0.0f;
  }
  const float scale = 0.08838834764831845f;  // 1/sqrt(128)

  const int jmax = q0 + QT;
  for (int j0 = 0; j0 < jmax; j0 += KT) {
    __syncthreads();
    for (int cch = tid; cch < KT * 32; cch += 256) {
      const int r = cch >> 5, col = (cch & 31) << 2;
      const float* src = &kv[((size_t)b * Ss + j0 + r) * 256];
      *(float4*)&Ks[r][col] = *(const float4*)&src[col];
      *(float4*)&Vs[r][col] = *(const float4*)&src[128 + col];
    }
    __syncthreads();

    float sc[4][2];
#pragma unroll
    for (int i = 0; i < 4; i++) { sc[i][0] = 0.0f; sc[i][1] = 0.0f; }
    for (int kk = 0; kk < DHd; kk += 4) {
      float4 a[4], bb[2];
#pragma unroll
      for (int i = 0; i < 4; i++) a[i] = *(const float4*)&Qs[ty + 16 * i][kk];
#pragma unroll
      for (int jj = 0; jj < 2; jj++) bb[jj] = *(const float4*)&Ks[tx + 16 * jj][kk];
#pragma unroll
      for (int i = 0; i < 4; i++)
#pragma unroll
        for (int jj = 0; jj < 2; jj++) {
          sc[i][jj] += a[i].x * bb[jj].x + a[i].y * bb[jj].y +
                       a[i].z * bb[jj].z + a[i].w * bb[jj].w;
        }
    }

#pragma unroll
    for (int i = 0; i < 4; i++) {
      const int gr = q0 + ty + 16 * i;
#pragma unroll
      for (int jj = 0; jj < 2; jj++) {
        const int gc = j0 + tx + 16 * jj;
        sc[i][jj] = (gc <= gr) ? sc[i][jj] * scale : -1e30f;
      }
    }

    float mt[4];
#pragma unroll
    for (int i = 0; i < 4; i++) mt[i] = fmaxf(sc[i][0], sc[i][1]);
#pragma unroll
    for (int off = 1; off < 16; off <<= 1)
#pragma unroll
      for (int i = 0; i < 4; i++) mt[i] = fmaxf(mt[i], __shfl_xor(mt[i], off));

    float alpha[4], p[4][2], rs[4];
#pragma unroll
    for (int i = 0; i < 4; i++) {
      const float mnew = fmaxf(m_i[i], mt[i]);
      alpha[i] = expf(m_i[i] - mnew);
      m_i[i] = mnew;
      p[i][0] = expf(sc[i][0] - mnew);
      p[i][1] = expf(sc[i][1] - mnew);
      rs[i] = p[i][0] + p[i][1];
    }
#pragma unroll
    for (int off = 1; off < 16; off <<= 1)
#pragma unroll
      for (int i = 0; i < 4; i++) rs[i] += __shfl_xor(rs[i], off);
#pragma unroll
    for (int i = 0; i < 4; i++) {
      l_i[i] = l_i[i] * alpha[i] + rs[i];
#pragma unroll
      for (int j = 0; j < 8; j++) O[i][j] *= alpha[i];
      Ps[ty + 16 * i][tx]      = p[i][0];
      Ps[ty + 16 * i][tx + 16] = p[i][1];
    }
    __syncthreads();

    for (int kk = 0; kk < KT; kk++) {
      float pr[4];
#pragma unroll
      for (int i = 0; i < 4; i++) pr[i] = Ps[ty + 16 * i][kk];
      const float4 v0 = *(const float4*)&Vs[kk][tx * 4];
      const float4 v1 = *(const float4*)&Vs[kk][64 + tx * 4];
#pragma unroll
      for (int i = 0; i < 4; i++) {
        O[i][0] += pr[i] * v0.x; O[i][1] += pr[i] * v0.y;
        O[i][2] += pr[i] * v0.z; O[i][3] += pr[i] * v0.w;
        O[i][4] += pr[i] * v1.x; O[i][5] += pr[i] * v1.y;
        O[i][6] += pr[i] * v1.z; O[i][7] += pr[i] * v1.w;
      }
    }
  }

  // epilogue: normalize, convert to bf16, store
#pragma unroll
  for (int i = 0; i < 4; i++) {
    const float inv = 1.0f / l_i[i];
    const int row = q0 + ty + 16 * i;
    unsigned short* dst = &attn[(((size_t)b * Ss + row) * Hh + h) * DHd];
    ushort4 o0, o1;
    o0.x = f2bf(O[i][0] * inv); o0.y = f2bf(O[i][1] * inv);
    o0.z = f2bf(O[i][2] * inv); o0.w = f2bf(O[i][3] * inv);
    o1.x = f2bf(O[i][4] * inv); o1.y = f2bf(O[i][5] * inv);
    o1.z = f2bf(O[i][6] * inv); o1.w = f2bf(O[i][7] * inv);
    *(ushort4*)&dst[tx * 4]      = o0;
    *(ushort4*)&dst[64 + tx * 4] = o1;
  }
}

// ---------------------------------------------------------------------------
extern "C" void kernel_launch(void* const* d_in, const int* in_sizes, int n_in,
                              void* d_out, int out_size, void* d_ws, size_t ws_size,
                              hipStream_t stream) {
  const float* x   = (const float*)d_in[0];   // (B,S,D)
  const float* qw  = (const float*)d_in[1];   // (H*DH, D)
  const float* qb  = (const float*)d_in[2];
  const float* kvw = (const float*)d_in[3];   // (256, D)
  const float* kvb = (const float*)d_in[4];
  const float* ow  = (const float*)d_in[5];   // (D, H*DH)
  const float* ob  = (const float*)d_in[6];
  float* out = (float*)d_out;

  // workspace layout (bytes):
  //   [0, 16.78M)   xb   (BS x D bf16)   -- later reused as attn_b
  //   [16.78M, 25.17M) qwb (D x D bf16)  -- later reused as owb
  //   [25.17M, 26.21M) kvwb (256 x D bf16)
  //   [26.21M, 59.77M) q_buf (BS x D fp32)
  //   [59.77M, 63.96M) kv_buf (BS x 256 fp32)
  char* wsb = (char*)d_ws;
  unsigned short* xb     = (unsigned short*)wsb;                       // 16.78 MB
  unsigned short* attn_b = xb;                                         // alias (xb dead after projections)
  unsigned short* qwb    = (unsigned short*)(wsb + 16777216);          // 8.39 MB
  unsigned short* owb    = qwb;                                        // alias (qwb dead after Q proj)
  unsigned short* kvwb   = (unsigned short*)(wsb + 25165824);          // 1.05 MB
  float*          q_buf  = (float*)(wsb + 26214400);                   // 33.55 MB
  float*          kv_buf = (float*)(wsb + 59768832);                   // 4.19 MB
  // total 63.96 MB

  // casts
  cast_f32_bf16<<<(BS * Dd / 4 + 255) / 256, 256, 0, stream>>>(x,   xb,   BS * Dd / 4);
  cast_f32_bf16<<<(Dd * Dd / 4 + 255) / 256, 256, 0, stream>>>(qw,  qwb,  Dd * Dd / 4);
  cast_f32_bf16<<<(256 * Dd / 4 + 255) / 256, 256, 0, stream>>>(kvw, kvwb, 256 * Dd / 4);

  // Q projection: (BS x 2048)
  gemm_bt_mfma<<<dim3(Dd / TN, BS / TM), 256, 0, stream>>>(
      xb, qwb, qb, q_buf, BS, Dd, Dd);
  // KV projection: (BS x 256)
  gemm_bt_mfma<<<dim3(256 / TN, BS / TM), 256, 0, stream>>>(
      xb, kvwb, kvb, kv_buf, BS, 256, Dd);

  // cast ow into the (now dead) qwb region
  cast_f32_bf16<<<(Dd * Dd / 4 + 255) / 256, 256, 0, stream>>>(ow, owb, Dd * Dd / 4);

  // RoPE in-place
  rope_kernel<<<BS, 64, 0, stream>>>(q_buf, kv_buf, Ss);

  // causal MQA flash attention -> bf16 attn (into dead xb region)
  flash_attn_f32<<<dim3(Ss / QT, Hh, Bb), 256, 0, stream>>>(q_buf, kv_buf, attn_b);

  // O projection: out = attn @ ow^T + ob
  gemm_bt_mfma<<<dim3(Dd / TN, BS / TM), 256, 0, stream>>>(
      attn_b, owb, ob, out, BS, Dd, Dd);
}

// Round 3
// 439.163 us; speedup vs baseline: 5.8206x; 3.2269x over previous
//
#include <hip/hip_runtime.h>
#include <math.h>

// Problem constants (fixed by the reference)
constexpr int Bb  = 2;
constexpr int Ss  = 2048;
constexpr int Dd  = 2048;
constexpr int Hh  = 16;
constexpr int DHd = 128;
constexpr int BS  = Bb * Ss;   // 4096

typedef __bf16 bf16x8 __attribute__((ext_vector_type(8)));
typedef float  f32x4  __attribute__((ext_vector_type(4)));

// fp32 -> bf16 (RNE), bit-level
static __device__ __forceinline__ unsigned short f2bf(float f) {
  union { float f; unsigned int u; } a; a.f = f;
  unsigned int u = a.u;
  unsigned int r = (u + 0x7fffu + ((u >> 16) & 1u)) >> 16;
  return (unsigned short)r;
}
static __device__ __forceinline__ float bf2f(unsigned short u) {
  union { unsigned int u; float f; } a; a.u = ((unsigned int)u) << 16;
  return a.f;
}

// ---------------------------------------------------------------------------
// cast fp32 -> bf16, one float4 per thread
// ---------------------------------------------------------------------------
__global__ __launch_bounds__(256) void cast_f32_bf16(
    const float* __restrict__ src, unsigned short* __restrict__ dst, int n4)
{
  const int i = blockIdx.x * 256 + threadIdx.x;
  if (i >= n4) return;
  const float4 v = ((const float4*)src)[i];
  ushort4 o;
  o.x = f2bf(v.x); o.y = f2bf(v.y); o.z = f2bf(v.z); o.w = f2bf(v.w);
  ((ushort4*)dst)[i] = o;
}

// ---------------------------------------------------------------------------
// bf16 MFMA GEMM: C[M][N] = A[M][K] @ Bw[N][K]^T + bias[N].
// 128x128 tile, BK=32, 256 threads (4 waves, 2x2 quadrants of 64x64),
// global_load_lds width-16 staging. Output fp32 or bf16 (template).
// ---------------------------------------------------------------------------
#define TM 128
#define TN 128
#define TK 32

#define GLOAD16(gp, lp)                                                        \
  __builtin_amdgcn_global_load_lds(                                            \
      (const __attribute__((address_space(1))) void*)(gp),                     \
      (__attribute__((address_space(3))) void*)(lp), 16, 0, 0)

template <bool BF16OUT>
__global__ __launch_bounds__(256) void gemm_bt_mfma(
    const unsigned short* __restrict__ A,    // M x K bf16
    const unsigned short* __restrict__ Bw,   // N x K bf16
    const float* __restrict__ bias,          // N
    void* __restrict__ Cv,                   // M x N (fp32 or bf16)
    int M, int N, int K)
{
  __shared__ unsigned short As[TM * TK];   // 8 KB
  __shared__ unsigned short Bs[TN * TK];   // 8 KB

  const int tid  = threadIdx.x;
  const int w    = tid >> 6;      // wave 0..3
  const int lane = tid & 63;
  const int m0   = blockIdx.y * TM;
  const int n0   = blockIdx.x * TN;
  const int wm   = (w >> 1) * 64;
  const int wn   = (w & 1) * 64;

  f32x4 acc[4][4];
#pragma unroll
  for (int i = 0; i < 4; i++)
#pragma unroll
    for (int j = 0; j < 4; j++) acc[i][j] = (f32x4){0.f, 0.f, 0.f, 0.f};

  const int srow = lane >> 2;          // 0..15
  const int scol = (lane & 3) * 8;
  const unsigned short* aG0 = A  + (size_t)(m0 +      w * 16 + srow) * K + scol;
  const unsigned short* aG1 = A  + (size_t)(m0 + 64 + w * 16 + srow) * K + scol;
  const unsigned short* bG0 = Bw + (size_t)(n0 +      w * 16 + srow) * K + scol;
  const unsigned short* bG1 = Bw + (size_t)(n0 + 64 + w * 16 + srow) * K + scol;
  unsigned short* aL0 = &As[(     w * 16) * TK];
  unsigned short* aL1 = &As[(64 + w * 16) * TK];
  unsigned short* bL0 = &Bs[(     w * 16) * TK];
  unsigned short* bL1 = &Bs[(64 + w * 16) * TK];

  const int fr = lane & 15;
  const int fk = (lane >> 4) * 8;

  for (int k0 = 0; k0 < K; k0 += TK) {
    __syncthreads();
    GLOAD16(aG0 + k0, aL0);
    GLOAD16(aG1 + k0, aL1);
    GLOAD16(bG0 + k0, bL0);
    GLOAD16(bG1 + k0, bL1);
    __syncthreads();

    bf16x8 af[4], bfr[4];
#pragma unroll
    for (int i = 0; i < 4; i++)
      af[i] = *(const bf16x8*)&As[(wm + i * 16 + fr) * TK + fk];
#pragma unroll
    for (int j = 0; j < 4; j++)
      bfr[j] = *(const bf16x8*)&Bs[(wn + j * 16 + fr) * TK + fk];
#pragma unroll
    for (int i = 0; i < 4; i++)
#pragma unroll
      for (int j = 0; j < 4; j++)
        acc[i][j] = __builtin_amdgcn_mfma_f32_16x16x32_bf16(
            af[i], bfr[j], acc[i][j], 0, 0, 0);
  }

  const int er = (lane >> 4) * 4;
  const int ec = lane & 15;
#pragma unroll
  for (int j = 0; j < 4; j++) {
    const int col = n0 + wn + j * 16 + ec;
    const float bv = bias[col];
#pragma unroll
    for (int i = 0; i < 4; i++) {
      const int rbase = m0 + wm + i * 16 + er;
#pragma unroll
      for (int r = 0; r < 4; r++) {
        const float v = acc[i][j][r] + bv;
        if constexpr (BF16OUT)
          ((unsigned short*)Cv)[(size_t)(rbase + r) * N + col] = f2bf(v);
        else
          ((float*)Cv)[(size_t)(rbase + r) * N + col] = v;
      }
    }
  }
}

// ---------------------------------------------------------------------------
// RoPE in-place on Qb bf16 (B,S,H*128). Block per (b,s) row, 256 threads:
// thread t: head t>>4, dims (t&15)*4..+3 paired with +64.
// ---------------------------------------------------------------------------
__global__ __launch_bounds__(256) void rope_q_bf16(unsigned short* __restrict__ Qb)
{
  const int row = blockIdx.x;        // b*S + s
  const int s   = row & (Ss - 1);
  const int t   = threadIdx.x;
  const int h   = t >> 4, p = t & 15;
  unsigned short* base = Qb + (size_t)row * Dd + h * DHd + p * 4;

  union { ushort4 v; unsigned short a[4]; } lo, hi, olo, ohi;
  lo.v = *(ushort4*)base;
  hi.v = *(ushort4*)(base + 64);
#pragma unroll
  for (int d = 0; d < 4; d++) {
    const int i = p * 4 + d;
    const float invf = exp2f(-(float)i * (13.287712379549449f / 64.0f)); // 10000^(-i/64)
    const float ang = (float)s * invf;
    const float c = cosf(ang), sn = sinf(ang);
    const float l = bf2f(lo.a[d]), hh = bf2f(hi.a[d]);
    olo.a[d] = f2bf(l * c - hh * sn);
    ohi.a[d] = f2bf(hh * c + l * sn);
  }
  *(ushort4*)base        = olo.v;
  *(ushort4*)(base + 64) = ohi.v;
}

// ---------------------------------------------------------------------------
// prep_kv: from KVb bf16 (B,S,256) produce
//   Kb (B,S,128) bf16 (roped k)  and  Vt (B,128,S) bf16 (transposed v).
// Block per 64 s-rows (grid BS/64), 256 threads.
// ---------------------------------------------------------------------------
__global__ __launch_bounds__(256) void prep_kv(
    const unsigned short* __restrict__ KVb,
    unsigned short* __restrict__ Kb,
    unsigned short* __restrict__ Vt)
{
  __shared__ unsigned short Vtile[64 * 136];   // [s_local][d], padded

  const int blk = blockIdx.x;          // b*32 + stile
  const int b   = blk >> 5;
  const int s0  = (blk & 31) * 64;
  const int t   = threadIdx.x;

  // --- rope K: thread t: row r=t>>2, dims (t&3)*16..+15 paired with +64
  {
    const int r = t >> 2, p = t & 3;
    const int row = blk * 64 + r;          // = b*Ss + s0 + r
    const int s = row & (Ss - 1);
    const unsigned short* src = KVb + (size_t)row * 256 + p * 16;
    union { uint4 v[2]; unsigned short a[16]; } lo, hi, ol, oh;
    lo.v[0] = *(const uint4*)src;        lo.v[1] = *(const uint4*)(src + 8);
    hi.v[0] = *(const uint4*)(src + 64); hi.v[1] = *(const uint4*)(src + 72);
#pragma unroll
    for (int e = 0; e < 16; e++) {
      const int i = p * 16 + e;
      const float invf = exp2f(-(float)i * (13.287712379549449f / 64.0f));
      const float ang = (float)s * invf;
      const float c = cosf(ang), sn = sinf(ang);
      const float l = bf2f(lo.a[e]), hh = bf2f(hi.a[e]);
      ol.a[e] = f2bf(l * c - hh * sn);
      oh.a[e] = f2bf(hh * c + l * sn);
    }
    unsigned short* dst = Kb + (size_t)row * 128 + p * 16;
    *(uint4*)dst        = ol.v[0]; *(uint4*)(dst + 8)  = ol.v[1];
    *(uint4*)(dst + 64) = oh.v[0]; *(uint4*)(dst + 72) = oh.v[1];
  }

  // --- stage V (cols 128..255) into LDS, s-major
#pragma unroll
  for (int c = 0; c < 4; c++) {
    const int id = c * 256 + t;
    const int vr = id >> 4, cc = id & 15;
    *(uint4*)&Vtile[vr * 136 + cc * 8] =
        *(const uint4*)(KVb + (size_t)(blk * 64 + vr) * 256 + 128 + cc * 8);
  }
  __syncthreads();

  // --- write Vt rows: thread t: d=t>>1, keys (t&1)*32..+31
  {
    const int d = t >> 1, half = t & 1;
    union { uint4 v[4]; unsigned short a[32]; } val;
#pragma unroll
    for (int kk = 0; kk < 32; kk++)
      val.a[kk] = Vtile[(half * 32 + kk) * 136 + d];
    unsigned short* dst = Vt + ((size_t)(b * 128 + d)) * Ss + s0 + half * 32;
#pragma unroll
    for (int c = 0; c < 4; c++) *(uint4*)(dst + c * 8) = val.v[c];
  }
}

// ---------------------------------------------------------------------------
// MFMA flash attention, causal MQA, all-bf16 inputs, fp32 softmax/accum.
// Grid: (S/128, H, B), 256 threads (4 waves x 32 q-rows). KT=64 keys/iter.
// ---------------------------------------------------------------------------
__global__ __launch_bounds__(256, 2) void flash_attn_mfma(
    const unsigned short* __restrict__ Qb,   // (B,S,H*128) bf16 roped
    const unsigned short* __restrict__ Kb,   // (B,S,128) bf16 roped
    const unsigned short* __restrict__ Vt,   // (B,128,S) bf16
    unsigned short* __restrict__ attn)       // (B,S,H*128) bf16
{
  __shared__ unsigned short Ks[64 * 136];    // [key][dh], padded  (17.4 KB)
  __shared__ unsigned short Vs[128 * 72];    // [dh][key], padded  (18.4 KB)
  __shared__ unsigned short Ps[128 * 72];    // per-wave 32 rows   (18.4 KB)

  const int qt = (int)gridDim.x - 1 - (int)blockIdx.x;  // heavy tiles first
  const int h = blockIdx.y, b = blockIdx.z;
  const int q0 = qt * 128;
  const int tid = threadIdx.x;
  const int w = tid >> 6, lane = tid & 63;
  const int lg = lane >> 4, lm = lane & 15;
  const int qrow_base = q0 + w * 32;

  // Q fragments (A-layout) in registers: aq[mtile][kfrag]
  bf16x8 aq[2][4];
#pragma unroll
  for (int mt = 0; mt < 2; mt++) {
    const unsigned short* qp =
        Qb + ((size_t)(b * Ss + qrow_base + mt * 16 + lm)) * Dd + h * DHd + lg * 8;
#pragma unroll
    for (int kf = 0; kf < 4; kf++) aq[mt][kf] = *(const bf16x8*)(qp + kf * 32);
  }

  f32x4 o[2][8], mi[2], li[2];
#pragma unroll
  for (int mt = 0; mt < 2; mt++) {
    mi[mt] = (f32x4){-1e30f, -1e30f, -1e30f, -1e30f};
    li[mt] = (f32x4){0.f, 0.f, 0.f, 0.f};
#pragma unroll
    for (int dt = 0; dt < 8; dt++) o[mt][dt] = (f32x4){0.f, 0.f, 0.f, 0.f};
  }

  unsigned short* Psw = &Ps[w * 32 * 72];
  const float sscale = 0.08838834764831845f * 1.4426950408889634f;  // /sqrt(128)*log2e
  const int jend = q0 + 128;
  const int wave_last = qrow_base + 31;

  for (int j0 = 0; j0 < jend; j0 += 64) {
    __syncthreads();   // previous iteration's LDS readers done
    {
      const unsigned short* kg = Kb + (size_t)(b * Ss + j0) * 128;
#pragma unroll
      for (int c = 0; c < 4; c++) {
        const int id = c * 256 + tid;
        const int r = id >> 4, cc = id & 15;
        *(uint4*)&Ks[r * 136 + cc * 8] = *(const uint4*)(kg + r * 128 + cc * 8);
      }
      const unsigned short* vg = Vt + (size_t)b * 128 * Ss + j0;
#pragma unroll
      for (int c = 0; c < 4; c++) {
        const int id = c * 256 + tid;
        const int d = id >> 3, cc = id & 7;
        *(uint4*)&Vs[d * 72 + cc * 8] = *(const uint4*)(vg + (size_t)d * Ss + cc * 8);
      }
    }
    __syncthreads();

    if (j0 <= wave_last) {   // wave-uniform: skip fully-masked key tiles
      // ---- QK^T
      f32x4 sc[2][4];
#pragma unroll
      for (int mt = 0; mt < 2; mt++)
#pragma unroll
        for (int nt = 0; nt < 4; nt++) sc[mt][nt] = (f32x4){0.f, 0.f, 0.f, 0.f};
#pragma unroll
      for (int nt = 0; nt < 4; nt++) {
        bf16x8 bk[4];
#pragma unroll
        for (int kf = 0; kf < 4; kf++)
          bk[kf] = *(const bf16x8*)&Ks[(nt * 16 + lm) * 136 + kf * 32 + lg * 8];
#pragma unroll
        for (int mt = 0; mt < 2; mt++)
#pragma unroll
          for (int kf = 0; kf < 4; kf++)
            sc[mt][nt] = __builtin_amdgcn_mfma_f32_16x16x32_bf16(
                aq[mt][kf], bk[kf], sc[mt][nt], 0, 0, 0);
      }

      // ---- scale (log2 domain) + causal mask
#pragma unroll
      for (int mt = 0; mt < 2; mt++)
#pragma unroll
        for (int nt = 0; nt < 4; nt++) {
          const int gc = j0 + nt * 16 + lm;
#pragma unroll
          for (int r = 0; r < 4; r++) {
            const int gr = qrow_base + mt * 16 + lg * 4 + r;
            sc[mt][nt][r] = (gc <= gr) ? sc[mt][nt][r] * sscale : -1e30f;
          }
        }

      // ---- row max (over nt regs, then over the 16 key lanes)
      f32x4 mrow[2];
#pragma unroll
      for (int mt = 0; mt < 2; mt++) {
        f32x4 m0 = sc[mt][0];
#pragma unroll
        for (int nt = 1; nt < 4; nt++)
#pragma unroll
          for (int r = 0; r < 4; r++) m0[r] = fmaxf(m0[r], sc[mt][nt][r]);
        mrow[mt] = m0;
      }
#pragma unroll
      for (int off = 1; off < 16; off <<= 1)
#pragma unroll
        for (int mt = 0; mt < 2; mt++)
#pragma unroll
          for (int r = 0; r < 4; r++)
            mrow[mt][r] = fmaxf(mrow[mt][r], __shfl_xor(mrow[mt][r], off));

      // ---- online softmax update
      f32x4 alpha[2], rs[2];
#pragma unroll
      for (int mt = 0; mt < 2; mt++) {
        rs[mt] = (f32x4){0.f, 0.f, 0.f, 0.f};
#pragma unroll
        for (int r = 0; r < 4; r++) {
          const float mn = fmaxf(mi[mt][r], mrow[mt][r]);
          alpha[mt][r] = exp2f(mi[mt][r] - mn);
          mi[mt][r] = mn;
        }
      }
#pragma unroll
      for (int mt = 0; mt < 2; mt++)
#pragma unroll
        for (int nt = 0; nt < 4; nt++)
#pragma unroll
          for (int r = 0; r < 4; r++) {
            const float pv = exp2f(sc[mt][nt][r] - mi[mt][r]);
            sc[mt][nt][r] = pv;
            rs[mt][r] += pv;
          }
#pragma unroll
      for (int off = 1; off < 16; off <<= 1)
#pragma unroll
        for (int mt = 0; mt < 2; mt++)
#pragma unroll
          for (int r = 0; r < 4; r++) rs[mt][r] += __shfl_xor(rs[mt][r], off);
#pragma unroll
      for (int mt = 0; mt < 2; mt++)
#pragma unroll
        for (int r = 0; r < 4; r++)
          li[mt][r] = li[mt][r] * alpha[mt][r] + rs[mt][r];

      // ---- rescale O, stash P to LDS (C-layout -> A-layout round trip)
#pragma unroll
      for (int mt = 0; mt < 2; mt++)
#pragma unroll
        for (int dt = 0; dt < 8; dt++)
#pragma unroll
          for (int r = 0; r < 4; r++) o[mt][dt][r] *= alpha[mt][r];
#pragma unroll
      for (int mt = 0; mt < 2; mt++)
#pragma unroll
        for (int nt = 0; nt < 4; nt++)
#pragma unroll
          for (int r = 0; r < 4; r++)
            Psw[(mt * 16 + lg * 4 + r) * 72 + nt * 16 + lm] = f2bf(sc[mt][nt][r]);

      // ---- PV (P and V both per-wave/LDS-resident; lgkmcnt orders write->read)
#pragma unroll
      for (int kf2 = 0; kf2 < 2; kf2++) {
        bf16x8 ap[2];
#pragma unroll
        for (int mt = 0; mt < 2; mt++)
          ap[mt] = *(const bf16x8*)&Psw[(mt * 16 + lm) * 72 + kf2 * 32 + lg * 8];
#pragma unroll
        for (int dt = 0; dt < 8; dt++) {
          const bf16x8 bv =
              *(const bf16x8*)&Vs[(dt * 16 + lm) * 72 + kf2 * 32 + lg * 8];
#pragma unroll
          for (int mt = 0; mt < 2; mt++)
            o[mt][dt] = __builtin_amdgcn_mfma_f32_16x16x32_bf16(
                ap[mt], bv, o[mt][dt], 0, 0, 0);
        }
      }
    }
  }

  // ---- epilogue: normalize, bf16, store
#pragma unroll
  for (int mt = 0; mt < 2; mt++) {
    f32x4 inv;
#pragma unroll
    for (int r = 0; r < 4; r++) inv[r] = 1.0f / li[mt][r];
#pragma unroll
    for (int r = 0; r < 4; r++) {
      const int row = qrow_base + mt * 16 + lg * 4 + r;
      unsigned short* dst = attn + ((size_t)(b * Ss + row)) * Dd + h * DHd + lm;
#pragma unroll
      for (int dt = 0; dt < 8; dt++)
        dst[dt * 16] = f2bf(o[mt][dt][r] * inv[r]);
    }
  }
}

// ---------------------------------------------------------------------------
extern "C" void kernel_launch(void* const* d_in, const int* in_sizes, int n_in,
                              void* d_out, int out_size, void* d_ws, size_t ws_size,
                              hipStream_t stream) {
  const float* x   = (const float*)d_in[0];   // (B,S,D)
  const float* qw  = (const float*)d_in[1];   // (H*DH, D)
  const float* qb  = (const float*)d_in[2];
  const float* kvw = (const float*)d_in[3];   // (256, D)
  const float* kvb = (const float*)d_in[4];
  const float* ow  = (const float*)d_in[5];   // (D, H*DH)
  const float* ob  = (const float*)d_in[6];
  float* out = (float*)d_out;

  // workspace layout (bytes):
  //   [0,        16.78M)  xb (BS x D bf16)      -> later reused as attn_b
  //   [16.78M,   25.17M)  qwb (D x D bf16)      -> later reused as owb
  //   [25.17M,   26.21M)  kvwb (256 x D bf16)
  //   [26.21M,   42.99M)  Qb  (BS x D bf16, roped in place)
  //   [42.99M,   45.09M)  KVb (BS x 256 bf16)
  //   [45.09M,   46.14M)  Kb  (B,S,128 bf16 roped)
  //   [46.14M,   47.19M)  Vt  (B,128,S bf16)
  char* wsb = (char*)d_ws;
  unsigned short* xb     = (unsigned short*)wsb;
  unsigned short* attn_b = xb;                               // alias, xb dead after projections
  unsigned short* qwb    = (unsigned short*)(wsb + 16777216);
  unsigned short* owb    = qwb;                              // alias, qwb dead after Q proj
  unsigned short* kvwb   = (unsigned short*)(wsb + 25165824);
  unsigned short* Qb     = (unsigned short*)(wsb + 26214400);
  unsigned short* KVb    = (unsigned short*)(wsb + 42991616);
  unsigned short* Kb     = (unsigned short*)(wsb + 45088768);
  unsigned short* Vt     = (unsigned short*)(wsb + 46137344);
  // total 47.19 MB

  // casts
  cast_f32_bf16<<<(BS * Dd / 4 + 255) / 256, 256, 0, stream>>>(x,   xb,   BS * Dd / 4);
  cast_f32_bf16<<<(Dd * Dd / 4 + 255) / 256, 256, 0, stream>>>(qw,  qwb,  Dd * Dd / 4);
  cast_f32_bf16<<<(256 * Dd / 4 + 255) / 256, 256, 0, stream>>>(kvw, kvwb, 256 * Dd / 4);

  // projections (bf16 out)
  gemm_bt_mfma<true><<<dim3(Dd / TN, BS / TM), 256, 0, stream>>>(
      xb, qwb, qb, Qb, BS, Dd, Dd);
  gemm_bt_mfma<true><<<dim3(256 / TN, BS / TM), 256, 0, stream>>>(
      xb, kvwb, kvb, KVb, BS, 256, Dd);

  // cast ow into the (now dead) qwb region
  cast_f32_bf16<<<(Dd * Dd / 4 + 255) / 256, 256, 0, stream>>>(ow, owb, Dd * Dd / 4);

  // RoPE + KV prep
  rope_q_bf16<<<BS, 256, 0, stream>>>(Qb);
  prep_kv<<<BS / 64, 256, 0, stream>>>(KVb, Kb, Vt);

  // MFMA flash attention -> bf16 attn (into dead xb region)
  flash_attn_mfma<<<dim3(Ss / 128, Hh, Bb), 256, 0, stream>>>(Qb, Kb, Vt, attn_b);

  // O projection: out = attn @ ow^T + ob (fp32 out)
  gemm_bt_mfma<false><<<dim3(Dd / TN, BS / TM), 256, 0, stream>>>(
      attn_b, owb, ob, out, BS, Dd, Dd);
}